// Round 1
// baseline (1327.370 us; speedup 1.0000x reference)
//
#include <hip/hip_runtime.h>
#include <hip/hip_bf16.h>
#include <stdint.h>
#include <stddef.h>

#define SEQL 2048
#define DIMSZ 2048
#define HN 16
#define DKD 128
#define DVD 128
#define QSCALE 0.08838834764831843f   // 128^-0.5

typedef __attribute__((ext_vector_type(4))) float f32x4;
typedef __attribute__((ext_vector_type(2))) float f32x2;
typedef __attribute__((ext_vector_type(8))) short bf16x8;

__device__ __forceinline__ float sigmoid_f(float x) { return 1.f / (1.f + __expf(-x)); }

// ---------------- bf16 GEMM: C[M,N] (f32) = A[M,K]bf16 @ Bt[N,K]bf16 ----------------
#define BM 128
#define BN 128
#define BKK 64

__global__ __launch_bounds__(256) void gemm_bt(
    const __hip_bfloat16* __restrict__ A, const __hip_bfloat16* __restrict__ B,
    float* __restrict__ C, int M, int N, int lda, int klen, int accum)
{
  __shared__ __hip_bfloat16 As[BM * BKK];
  __shared__ __hip_bfloat16 Bs[BN * BKK];
  const int tid = threadIdx.x;
  const int lane = tid & 63;
  const int w = tid >> 6;
  const int wm = w >> 1, wn = w & 1;            // 2x2 wave grid, 64x64 each
  const int m0 = blockIdx.y * BM, n0 = blockIdx.x * BN;
  const int l15 = lane & 15, l4 = lane >> 4;
  const int kbase = blockIdx.z * klen;

  f32x4 acc[4][4] = {};

  for (int k0 = kbase; k0 < kbase + klen; k0 += BKK) {
#pragma unroll
    for (int i = 0; i < 4; ++i) {
      const int c = (w * 4 + i) * 64 + lane;     // chunk id, 16B each; 8 chunks/row
      const int row = c >> 3;
      const int colb = (c & 7) * 8;
      __builtin_amdgcn_global_load_lds(
          (const __attribute__((address_space(1))) void*)(A + (size_t)(m0 + row) * lda + k0 + colb),
          (__attribute__((address_space(3))) void*)(As + (size_t)c * 8), 16, 0, 0);
      __builtin_amdgcn_global_load_lds(
          (const __attribute__((address_space(1))) void*)(B + (size_t)(n0 + row) * lda + k0 + colb),
          (__attribute__((address_space(3))) void*)(Bs + (size_t)c * 8), 16, 0, 0);
    }
    __syncthreads();
#pragma unroll
    for (int kk = 0; kk < BKK; kk += 32) {
      bf16x8 af[4], bfv[4];
#pragma unroll
      for (int mi = 0; mi < 4; ++mi)
        af[mi] = *(const bf16x8*)(As + (wm * 64 + mi * 16 + l15) * BKK + kk + l4 * 8);
#pragma unroll
      for (int ni = 0; ni < 4; ++ni)
        bfv[ni] = *(const bf16x8*)(Bs + (wn * 64 + ni * 16 + l15) * BKK + kk + l4 * 8);
#pragma unroll
      for (int mi = 0; mi < 4; ++mi)
#pragma unroll
        for (int ni = 0; ni < 4; ++ni)
          acc[mi][ni] = __builtin_amdgcn_mfma_f32_16x16x32_bf16(af[mi], bfv[ni], acc[mi][ni], 0, 0, 0);
    }
    __syncthreads();
  }

  float* Cz = C + (size_t)blockIdx.z * M * N;
#pragma unroll
  for (int mi = 0; mi < 4; ++mi) {
#pragma unroll
    for (int ni = 0; ni < 4; ++ni) {
      const int row = m0 + wm * 64 + mi * 16 + l4 * 4;
      const int col = n0 + wn * 64 + ni * 16 + l15;
#pragma unroll
      for (int r = 0; r < 4; ++r) {
        size_t idx = (size_t)(row + r) * N + col;
        if (accum) Cz[idx] += acc[mi][ni][r];
        else Cz[idx] = acc[mi][ni][r];
      }
    }
  }
}

// ---------------- transpose + cast (optional hi/lo split): out[C,R] = bf16(in[R,C]^T) ----------------
__global__ __launch_bounds__(256) void transpose_cast_kernel(
    const float* __restrict__ in, __hip_bfloat16* __restrict__ outT,
    __hip_bfloat16* __restrict__ outLo, int R, int C)
{
  __shared__ float tile[32][33];
  const int c0 = blockIdx.x * 32, r0 = blockIdx.y * 32;
  const int tc = threadIdx.x & 31, tr = threadIdx.x >> 5;   // tr in 0..7
#pragma unroll
  for (int i = 0; i < 4; ++i)
    tile[tr + i * 8][tc] = in[(size_t)(r0 + tr + i * 8) * C + c0 + tc];
  __syncthreads();
#pragma unroll
  for (int i = 0; i < 4; ++i) {
    float val = tile[tc][tr + i * 8];
    __hip_bfloat16 h = __float2bfloat16(val);
    size_t oi = (size_t)(c0 + tr + i * 8) * R + r0 + tc;
    outT[oi] = h;
    if (outLo) outLo[oi] = __float2bfloat16(val - __bfloat162float(h));
  }
}

// ---------------- elementwise cast with optional lo residual ----------------
__global__ __launch_bounds__(256) void cast_split_kernel(
    const float* __restrict__ in, __hip_bfloat16* __restrict__ hi,
    __hip_bfloat16* __restrict__ lo, int n4)
{
  int idx = blockIdx.x * 256 + threadIdx.x;
  if (idx >= n4) return;
  f32x4 v = *(const f32x4*)(in + (size_t)idx * 4);
  union { __hip_bfloat16 b[4]; unsigned long long u; } ph, pl;
#pragma unroll
  for (int j = 0; j < 4; ++j) {
    float f = v[j];
    __hip_bfloat16 hh = __float2bfloat16(f);
    ph.b[j] = hh;
    pl.b[j] = __float2bfloat16(f - __bfloat162float(hh));
  }
  *(unsigned long long*)((char*)hi + (size_t)idx * 8) = ph.u;
  if (lo) *(unsigned long long*)((char*)lo + (size_t)idx * 8) = pl.u;
}

// ---------------- split-K reduce (8 partials) -> bf16 hi (+ optional lo) ----------------
__global__ __launch_bounds__(256) void reduce8_kernel(
    const float* __restrict__ part, __hip_bfloat16* __restrict__ hi,
    __hip_bfloat16* __restrict__ lo, int n4)
{
  int idx = blockIdx.x * 256 + threadIdx.x;
  if (idx >= n4) return;
  const size_t chunk = (size_t)SEQL * DVD;   // 2048*128
  f32x4 a = *(const f32x4*)(part + (size_t)idx * 4);
#pragma unroll
  for (int z = 1; z < 8; ++z) {
    f32x4 b = *(const f32x4*)(part + z * chunk + (size_t)idx * 4);
    a.x += b.x; a.y += b.y; a.z += b.z; a.w += b.w;
  }
  union { __hip_bfloat16 b[4]; unsigned long long u; } ph, pl;
#pragma unroll
  for (int j = 0; j < 4; ++j) {
    float f = a[j];
    __hip_bfloat16 hh = __float2bfloat16(f);
    ph.b[j] = hh;
    pl.b[j] = __float2bfloat16(f - __bfloat162float(hh));
  }
  *(unsigned long long*)((char*)hi + (size_t)idx * 8) = ph.u;
  if (lo) *(unsigned long long*)((char*)lo + (size_t)idx * 8) = pl.u;
}

// ---------------- causal depthwise conv (K=4) + silu, optional ve mix ----------------
__global__ __launch_bounds__(256) void conv_silu_kernel(
    const float* __restrict__ xin, const float* __restrict__ w,
    float* __restrict__ out, const float* __restrict__ ve,
    const float* __restrict__ lambdas)
{
  int idx = blockIdx.x * 256 + threadIdx.x;          // SEQL * 512
  int s = idx >> 9, c4 = idx & 511;
  int c = c4 * 4;
  f32x4 w0 = *(const f32x4*)(w + (size_t)(c + 0) * 4);
  f32x4 w1 = *(const f32x4*)(w + (size_t)(c + 1) * 4);
  f32x4 w2 = *(const f32x4*)(w + (size_t)(c + 2) * 4);
  f32x4 w3 = *(const f32x4*)(w + (size_t)(c + 3) * 4);
  f32x4 acc = {0.f, 0.f, 0.f, 0.f};
#pragma unroll
  for (int i = 0; i < 4; ++i) {
    int sr = s - 3 + i;
    if (sr >= 0) {
      f32x4 xv = *(const f32x4*)(xin + (size_t)sr * 2048 + c);
      acc.x = fmaf(xv.x, w0[i], acc.x);
      acc.y = fmaf(xv.y, w1[i], acc.y);
      acc.z = fmaf(xv.z, w2[i], acc.z);
      acc.w = fmaf(xv.w, w3[i], acc.w);
    }
  }
  f32x4 y;
  y.x = acc.x * sigmoid_f(acc.x);
  y.y = acc.y * sigmoid_f(acc.y);
  y.z = acc.z * sigmoid_f(acc.z);
  y.w = acc.w * sigmoid_f(acc.w);
  if (ve) {
    float l0 = lambdas[0], l1 = lambdas[1];
    f32x4 vv = *(const f32x4*)(ve + (size_t)idx * 4);
    y.x = l0 * y.x + l1 * vv.x;
    y.y = l0 * y.y + l1 * vv.y;
    y.z = l0 * y.z + l1 * vv.z;
    y.w = l0 * y.w + l1 * vv.w;
  }
  *(f32x4*)(out + (size_t)idx * 4) = y;
}

// ---------------- in-place l2norm over rows of 128, one wave per row ----------------
__global__ __launch_bounds__(256) void l2norm_kernel(float* __restrict__ t, float scale)
{
  int row = blockIdx.x * 4 + (threadIdx.x >> 6);
  int lane = threadIdx.x & 63;
  float* p = t + (size_t)row * 128 + lane * 2;
  f32x2 v = *(const f32x2*)p;
  float ss = v.x * v.x + v.y * v.y;
#pragma unroll
  for (int off = 32; off > 0; off >>= 1) ss += __shfl_xor(ss, off);
  float r = rsqrtf(ss + 1e-6f) * scale;
  f32x2 o; o.x = v.x * r; o.y = v.y * r;
  *(f32x2*)p = o;
}

// ---------------- gate prep: g -> exp(-exp(A_log[h]) * softplus(g + dt_bias)) in-place ----------------
__global__ __launch_bounds__(256) void gexp_kernel(
    float* __restrict__ g, const float* __restrict__ A_log, const float* __restrict__ dt_bias)
{
  int idx = blockIdx.x * 256 + threadIdx.x;      // over S2/4
  int c4 = idx & 511;
  int cbase = c4 * 4;
  int h = cbase >> 7;
  float a = expf(A_log[h]);
  f32x4 v = *(const f32x4*)(g + (size_t)idx * 4);
  f32x4 db = *(const f32x4*)(dt_bias + cbase);
#pragma unroll
  for (int j = 0; j < 4; ++j) {
    float val = v[j] + db[j];
    float sp = (val > 20.f) ? val : log1pf(expf(fminf(val, 20.f)));
    v[j] = expf(-a * sp);
  }
  *(f32x4*)(g + (size_t)idx * 4) = v;
}

// ---------------- beta = sigmoid(x @ Wb), thread per (s,h) ----------------
__global__ __launch_bounds__(256) void beta_kernel(
    const float* __restrict__ x, const float* __restrict__ Wb, float* __restrict__ beta)
{
  int idx = blockIdx.x * 256 + threadIdx.x;      // 0..32767
  int s = idx >> 4, h = idx & 15;
  const float* xr = x + (size_t)s * DIMSZ;
  float acc = 0.f;
  for (int d = 0; d < DIMSZ; d += 4) {
    f32x4 xv = *(const f32x4*)(xr + d);
    acc = fmaf(xv.x, Wb[(size_t)(d + 0) * HN + h], acc);
    acc = fmaf(xv.y, Wb[(size_t)(d + 1) * HN + h], acc);
    acc = fmaf(xv.z, Wb[(size_t)(d + 2) * HN + h], acc);
    acc = fmaf(xv.w, Wb[(size_t)(d + 3) * HN + h], acc);
  }
  beta[idx] = 1.f / (1.f + expf(-acc));
}

// ---------------- DPP 16-lane row reduction (all lanes get the sum) ----------------
__device__ __forceinline__ float rowsum16(float x)
{
  union fi { float f; int i; };
  fi a, t; a.f = x;
  t.i = __builtin_amdgcn_update_dpp(0, a.i, 0x128, 0xf, 0xf, true); a.f += t.f; // row_ror:8
  t.i = __builtin_amdgcn_update_dpp(0, a.i, 0x124, 0xf, 0xf, true); a.f += t.f; // row_ror:4
  t.i = __builtin_amdgcn_update_dpp(0, a.i, 0x122, 0xf, 0xf, true); a.f += t.f; // row_ror:2
  t.i = __builtin_amdgcn_update_dpp(0, a.i, 0x121, 0xf, 0xf, true); a.f += t.f; // row_ror:1
  return a.f;
}

// ---------------- gated delta-rule recurrence ----------------
// 2048 independent (head, v-col) recurrences; 16 lanes/col, 8 state elems/lane.
__global__ __launch_bounds__(128) void kda_rec_kernel(
    const float* __restrict__ qn, const float* __restrict__ kn,
    const float* __restrict__ vv, const float* __restrict__ ge,
    const float* __restrict__ bet, float* __restrict__ o)
{
  const int h = blockIdx.x >> 4;
  const int cg = blockIdx.x & 15;
  const int tid = threadIdx.x;
  const int col = cg * 8 + (tid >> 4);
  const int sub = tid & 15;
  const size_t base = (size_t)h * 128 + sub * 8;
  const float* pk = kn + base;
  const float* pq = qn + base;
  const float* pe = ge + base;
  const float* pv = vv + (size_t)h * 128 + col;
  const float* pb = bet + h;
  float* po = o + (size_t)h * 128 + col;

  float S0 = 0, S1 = 0, S2 = 0, S3 = 0, S4 = 0, S5 = 0, S6 = 0, S7 = 0;
  f32x4 k0 = *(const f32x4*)pk, k1 = *(const f32x4*)(pk + 4);
  f32x4 e0 = *(const f32x4*)pe, e1 = *(const f32x4*)(pe + 4);
  f32x4 q0 = *(const f32x4*)pq, q1 = *(const f32x4*)(pq + 4);
  float vt = *pv, bt = *pb;

  auto stepf = [&](int t) {
    S0 *= e0.x; S1 *= e0.y; S2 *= e0.z; S3 *= e0.w;
    S4 *= e1.x; S5 *= e1.y; S6 *= e1.z; S7 *= e1.w;
    float pa = k0.x * S0; pa = fmaf(k0.y, S1, pa);
    float pb2 = k0.z * S2; pb2 = fmaf(k0.w, S3, pb2);
    float pc = k1.x * S4; pc = fmaf(k1.y, S5, pc);
    float pd = k1.z * S6; pd = fmaf(k1.w, S7, pd);
    float pred = rowsum16((pa + pb2) + (pc + pd));
    float vnew = bt * (vt - pred);
    S0 = fmaf(k0.x, vnew, S0); S1 = fmaf(k0.y, vnew, S1);
    S2 = fmaf(k0.z, vnew, S2); S3 = fmaf(k0.w, vnew, S3);
    S4 = fmaf(k1.x, vnew, S4); S5 = fmaf(k1.y, vnew, S5);
    S6 = fmaf(k1.z, vnew, S6); S7 = fmaf(k1.w, vnew, S7);
    float oa = q0.x * S0; oa = fmaf(q0.y, S1, oa);
    float ob = q0.z * S2; ob = fmaf(q0.w, S3, ob);
    float oc = q1.x * S4; oc = fmaf(q1.y, S5, oc);
    float od = q1.z * S6; od = fmaf(q1.w, S7, od);
    float out = rowsum16((oa + ob) + (oc + od));
    if (sub == 0) po[(size_t)t * 2048] = out;
  };

  for (int t = 0; t < SEQL - 1; ++t) {
    size_t off = (size_t)(t + 1) * 2048;
    f32x4 nk0 = *(const f32x4*)(pk + off), nk1 = *(const f32x4*)(pk + off + 4);
    f32x4 ne0 = *(const f32x4*)(pe + off), ne1 = *(const f32x4*)(pe + off + 4);
    f32x4 nq0 = *(const f32x4*)(pq + off), nq1 = *(const f32x4*)(pq + off + 4);
    float nv = pv[off], nb = pb[(size_t)(t + 1) * 16];
    stepf(t);
    k0 = nk0; k1 = nk1; e0 = ne0; e1 = ne1; q0 = nq0; q1 = nq1; vt = nv; bt = nb;
  }
  stepf(SEQL - 1);
}

// ---------------- sigmoid-gated RMSNorm -> bf16 ----------------
__global__ __launch_bounds__(256) void rmsgate_kernel(
    const float* __restrict__ o, const float* __restrict__ gate,
    const float* __restrict__ bg2, const float* __restrict__ norm_w,
    __hip_bfloat16* __restrict__ og)
{
  int row = blockIdx.x * 4 + (threadIdx.x >> 6);   // s*16 + h
  int lane = threadIdx.x & 63;
  int s = row >> 4, h = row & 15;
  int j = lane * 2;
  const float* p = o + (size_t)row * 128 + j;
  f32x2 v = *(const f32x2*)p;
  float ss = v.x * v.x + v.y * v.y;
#pragma unroll
  for (int off = 32; off > 0; off >>= 1) ss += __shfl_xor(ss, off);
  float rs = rsqrtf(ss * (1.f / 128.f) + 1e-6f);
  int c = h * 128 + j;
  float g0 = gate[(size_t)s * 2048 + c] + bg2[c];
  float g1 = gate[(size_t)s * 2048 + c + 1] + bg2[c + 1];
  float o0 = v.x * rs * norm_w[j] * (1.f / (1.f + expf(-g0)));
  float o1 = v.y * rs * norm_w[j + 1] * (1.f / (1.f + expf(-g1)));
  union { __hip_bfloat16 b[2]; unsigned int u; } pk2;
  pk2.b[0] = __float2bfloat16(o0);
  pk2.b[1] = __float2bfloat16(o1);
  *(unsigned int*)((char*)og + ((size_t)s * 2048 + c) * 2) = pk2.u;
}

// =====================================================================
extern "C" void kernel_launch(void* const* d_in, const int* in_sizes, int n_in,
                              void* d_out, int out_size, void* d_ws, size_t ws_size,
                              hipStream_t stream)
{
  const float* x      = (const float*)d_in[0];
  const float* ve     = (const float*)d_in[1];
  const float* lam    = (const float*)d_in[2];
  const float* Wq     = (const float*)d_in[3];
  const float* Wk     = (const float*)d_in[4];
  const float* Wv     = (const float*)d_in[5];
  const float* cwq    = (const float*)d_in[6];
  const float* cwk    = (const float*)d_in[7];
  const float* cwv    = (const float*)d_in[8];
  const float* Wf1    = (const float*)d_in[9];
  const float* Wf2    = (const float*)d_in[10];
  const float* Wb     = (const float*)d_in[11];
  const float* A_log  = (const float*)d_in[12];
  const float* dtb    = (const float*)d_in[13];
  const float* Wg1    = (const float*)d_in[14];
  const float* Wg2    = (const float*)d_in[15];
  const float* bg2    = (const float*)d_in[16];
  const float* norm_w = (const float*)d_in[17];
  const float* Wo     = (const float*)d_in[18];
  float* out = (float*)d_out;

  const size_t S2 = (size_t)2048 * 2048;

  char* p = (char*)d_ws;
  auto alloc = [&](size_t bytes) { char* r = p; p += (bytes + 255) & ~(size_t)255; return r; };

  __hip_bfloat16* xb    = (__hip_bfloat16*)alloc(S2 * 2);
  __hip_bfloat16* xlo   = (__hip_bfloat16*)alloc(S2 * 2);
  __hip_bfloat16* WqT   = (__hip_bfloat16*)alloc(S2 * 2);
  __hip_bfloat16* WkT   = (__hip_bfloat16*)alloc(S2 * 2);
  __hip_bfloat16* WvT   = (__hip_bfloat16*)alloc(S2 * 2);
  __hip_bfloat16* WoT   = (__hip_bfloat16*)alloc(S2 * 2);
  __hip_bfloat16* Wf1hT = (__hip_bfloat16*)alloc(2048 * 128 * 2);
  __hip_bfloat16* Wf1lT = (__hip_bfloat16*)alloc(2048 * 128 * 2);
  __hip_bfloat16* Wf2hT = (__hip_bfloat16*)alloc(2048 * 128 * 2);
  __hip_bfloat16* Wf2lT = (__hip_bfloat16*)alloc(2048 * 128 * 2);
  __hip_bfloat16* Wg1T  = (__hip_bfloat16*)alloc(2048 * 128 * 2);
  __hip_bfloat16* Wg2T  = (__hip_bfloat16*)alloc(2048 * 128 * 2);
  float* xq   = (float*)alloc(S2 * 4);   // later aliased: g / gexp
  float* xk   = (float*)alloc(S2 * 4);   // later aliased: gate
  float* xv   = (float*)alloc(S2 * 4);   // later aliased: o
  float* cq   = (float*)alloc(S2 * 4);
  float* ck   = (float*)alloc(S2 * 4);
  float* cv   = (float*)alloc(S2 * 4);
  __hip_bfloat16* f1h = (__hip_bfloat16*)alloc(2048 * 128 * 2);
  __hip_bfloat16* f1l = (__hip_bfloat16*)alloc(2048 * 128 * 2);
  __hip_bfloat16* g1b = (__hip_bfloat16*)alloc(2048 * 128 * 2);
  float* fpart = (float*)alloc((size_t)8 * 2048 * 128 * 4);
  float* betab = (float*)alloc((size_t)2048 * 16 * 4);
  __hip_bfloat16* og = (__hip_bfloat16*)alloc(S2 * 2);

  float* gbuf    = xq;   // aliases (dead after convs)
  float* gatebuf = xk;
  float* obuf    = xv;

  // 1. split-cast x
  cast_split_kernel<<<4096, 256, 0, stream>>>(x, xb, xlo, (int)(S2 / 4));

  // 2. weight transposes (+ hi/lo for the decay path)
  transpose_cast_kernel<<<dim3(64, 64), 256, 0, stream>>>(Wq, WqT, nullptr, 2048, 2048);
  transpose_cast_kernel<<<dim3(64, 64), 256, 0, stream>>>(Wk, WkT, nullptr, 2048, 2048);
  transpose_cast_kernel<<<dim3(64, 64), 256, 0, stream>>>(Wv, WvT, nullptr, 2048, 2048);
  transpose_cast_kernel<<<dim3(64, 64), 256, 0, stream>>>(Wo, WoT, nullptr, 2048, 2048);
  transpose_cast_kernel<<<dim3(4, 64), 256, 0, stream>>>(Wf1, Wf1hT, Wf1lT, 2048, 128);
  transpose_cast_kernel<<<dim3(64, 4), 256, 0, stream>>>(Wf2, Wf2hT, Wf2lT, 128, 2048);
  transpose_cast_kernel<<<dim3(4, 64), 256, 0, stream>>>(Wg1, Wg1T, nullptr, 2048, 128);
  transpose_cast_kernel<<<dim3(64, 4), 256, 0, stream>>>(Wg2, Wg2T, nullptr, 128, 2048);

  // 3. projection GEMMs
  gemm_bt<<<dim3(16, 16), 256, 0, stream>>>(xb, WqT, xq, 2048, 2048, 2048, 2048, 0);
  gemm_bt<<<dim3(16, 16), 256, 0, stream>>>(xb, WkT, xk, 2048, 2048, 2048, 2048, 0);
  gemm_bt<<<dim3(16, 16), 256, 0, stream>>>(xb, WvT, xv, 2048, 2048, 2048, 2048, 0);

  // 4. conv + silu (+ ve mix for v)
  conv_silu_kernel<<<4096, 256, 0, stream>>>(xq, cwq, cq, nullptr, nullptr);
  conv_silu_kernel<<<4096, 256, 0, stream>>>(xk, cwk, ck, nullptr, nullptr);
  conv_silu_kernel<<<4096, 256, 0, stream>>>(xv, cwv, cv, ve, lam);

  // 5. l2 norms
  l2norm_kernel<<<8192, 256, 0, stream>>>(cq, QSCALE);
  l2norm_kernel<<<8192, 256, 0, stream>>>(ck, 1.0f);

  // 6. f1 = x @ Wf1 (split precision, split-K z=8)
  gemm_bt<<<dim3(1, 16, 8), 256, 0, stream>>>(xb,  Wf1hT, fpart, 2048, 128, 2048, 256, 0);
  gemm_bt<<<dim3(1, 16, 8), 256, 0, stream>>>(xlo, Wf1hT, fpart, 2048, 128, 2048, 256, 1);
  gemm_bt<<<dim3(1, 16, 8), 256, 0, stream>>>(xb,  Wf1lT, fpart, 2048, 128, 2048, 256, 1);
  reduce8_kernel<<<256, 256, 0, stream>>>(fpart, f1h, f1l, 65536);

  // 7. g = f1 @ Wf2 (split precision) -> gbuf, then gate-exp in place
  gemm_bt<<<dim3(16, 16), 256, 0, stream>>>(f1h, Wf2hT, gbuf, 2048, 2048, 128, 128, 0);
  gemm_bt<<<dim3(16, 16), 256, 0, stream>>>(f1l, Wf2hT, gbuf, 2048, 2048, 128, 128, 1);
  gemm_bt<<<dim3(16, 16), 256, 0, stream>>>(f1h, Wf2lT, gbuf, 2048, 2048, 128, 128, 1);
  gexp_kernel<<<4096, 256, 0, stream>>>(gbuf, A_log, dtb);

  // 8. gate path (plain bf16 is fine through a sigmoid)
  gemm_bt<<<dim3(1, 16, 8), 256, 0, stream>>>(xb, Wg1T, fpart, 2048, 128, 2048, 256, 0);
  reduce8_kernel<<<256, 256, 0, stream>>>(fpart, g1b, nullptr, 65536);
  gemm_bt<<<dim3(16, 16), 256, 0, stream>>>(g1b, Wg2T, gatebuf, 2048, 2048, 128, 128, 0);

  // 9. beta
  beta_kernel<<<128, 256, 0, stream>>>(x, Wb, betab);

  // 10. recurrence
  kda_rec_kernel<<<256, 128, 0, stream>>>(cq, ck, cv, gbuf, betab, obuf);

  // 11. gated rmsnorm -> bf16
  rmsgate_kernel<<<8192, 256, 0, stream>>>(obuf, gatebuf, bg2, norm_w, og);

  // 12. output projection
  gemm_bt<<<dim3(16, 16), 256, 0, stream>>>(og, WoT, out, 2048, 2048, 2048, 2048, 0);
}

// Round 2
// 962.010 us; speedup vs baseline: 1.3798x; 1.3798x over previous
//
#include <hip/hip_runtime.h>
#include <hip/hip_bf16.h>
#include <stdint.h>
#include <stddef.h>

#define SEQL 2048
#define DIMSZ 2048
#define HN 16
#define DKD 128
#define DVD 128
#define QSCALE 0.08838834764831843f   // 128^-0.5

typedef __attribute__((ext_vector_type(4))) float f32x4;
typedef __attribute__((ext_vector_type(2))) float f32x2;
typedef __attribute__((ext_vector_type(8))) short bf16x8;

__device__ __forceinline__ float sigmoid_f(float x) { return 1.f / (1.f + __expf(-x)); }

// ---------------- bf16 GEMM: C[M,N] (f32) = A[M,K]bf16 @ Bt[N,K]bf16 ----------------
#define BM 128
#define BN 128
#define BKK 64

__global__ __launch_bounds__(256) void gemm_bt(
    const __hip_bfloat16* __restrict__ A, const __hip_bfloat16* __restrict__ B,
    float* __restrict__ C, int M, int N, int lda, int klen, int accum)
{
  __shared__ __hip_bfloat16 As[BM * BKK];
  __shared__ __hip_bfloat16 Bs[BN * BKK];
  const int tid = threadIdx.x;
  const int lane = tid & 63;
  const int w = tid >> 6;
  const int wm = w >> 1, wn = w & 1;            // 2x2 wave grid, 64x64 each
  const int m0 = blockIdx.y * BM, n0 = blockIdx.x * BN;
  const int l15 = lane & 15, l4 = lane >> 4;
  const int kbase = blockIdx.z * klen;

  f32x4 acc[4][4] = {};

  for (int k0 = kbase; k0 < kbase + klen; k0 += BKK) {
#pragma unroll
    for (int i = 0; i < 4; ++i) {
      const int c = (w * 4 + i) * 64 + lane;     // chunk id, 16B each; 8 chunks/row
      const int row = c >> 3;
      const int colb = (c & 7) * 8;
      __builtin_amdgcn_global_load_lds(
          (const __attribute__((address_space(1))) void*)(A + (size_t)(m0 + row) * lda + k0 + colb),
          (__attribute__((address_space(3))) void*)(As + (size_t)c * 8), 16, 0, 0);
      __builtin_amdgcn_global_load_lds(
          (const __attribute__((address_space(1))) void*)(B + (size_t)(n0 + row) * lda + k0 + colb),
          (__attribute__((address_space(3))) void*)(Bs + (size_t)c * 8), 16, 0, 0);
    }
    __syncthreads();
#pragma unroll
    for (int kk = 0; kk < BKK; kk += 32) {
      bf16x8 af[4], bfv[4];
#pragma unroll
      for (int mi = 0; mi < 4; ++mi)
        af[mi] = *(const bf16x8*)(As + (wm * 64 + mi * 16 + l15) * BKK + kk + l4 * 8);
#pragma unroll
      for (int ni = 0; ni < 4; ++ni)
        bfv[ni] = *(const bf16x8*)(Bs + (wn * 64 + ni * 16 + l15) * BKK + kk + l4 * 8);
#pragma unroll
      for (int mi = 0; mi < 4; ++mi)
#pragma unroll
        for (int ni = 0; ni < 4; ++ni)
          acc[mi][ni] = __builtin_amdgcn_mfma_f32_16x16x32_bf16(af[mi], bfv[ni], acc[mi][ni], 0, 0, 0);
    }
    __syncthreads();
  }

  float* Cz = C + (size_t)blockIdx.z * M * N;
#pragma unroll
  for (int mi = 0; mi < 4; ++mi) {
#pragma unroll
    for (int ni = 0; ni < 4; ++ni) {
      const int row = m0 + wm * 64 + mi * 16 + l4 * 4;
      const int col = n0 + wn * 64 + ni * 16 + l15;
#pragma unroll
      for (int r = 0; r < 4; ++r) {
        size_t idx = (size_t)(row + r) * N + col;
        if (accum) Cz[idx] += acc[mi][ni][r];
        else Cz[idx] = acc[mi][ni][r];
      }
    }
  }
}

// ---------------- transpose + cast (optional hi/lo split): out[C,R] = bf16(in[R,C]^T) ----------------
__global__ __launch_bounds__(256) void transpose_cast_kernel(
    const float* __restrict__ in, __hip_bfloat16* __restrict__ outT,
    __hip_bfloat16* __restrict__ outLo, int R, int C)
{
  __shared__ float tile[32][33];
  const int c0 = blockIdx.x * 32, r0 = blockIdx.y * 32;
  const int tc = threadIdx.x & 31, tr = threadIdx.x >> 5;   // tr in 0..7
#pragma unroll
  for (int i = 0; i < 4; ++i)
    tile[tr + i * 8][tc] = in[(size_t)(r0 + tr + i * 8) * C + c0 + tc];
  __syncthreads();
#pragma unroll
  for (int i = 0; i < 4; ++i) {
    float val = tile[tc][tr + i * 8];
    __hip_bfloat16 h = __float2bfloat16(val);
    size_t oi = (size_t)(c0 + tr + i * 8) * R + r0 + tc;
    outT[oi] = h;
    if (outLo) outLo[oi] = __float2bfloat16(val - __bfloat162float(h));
  }
}

// ---------------- elementwise cast with optional lo residual ----------------
__global__ __launch_bounds__(256) void cast_split_kernel(
    const float* __restrict__ in, __hip_bfloat16* __restrict__ hi,
    __hip_bfloat16* __restrict__ lo, int n4)
{
  int idx = blockIdx.x * 256 + threadIdx.x;
  if (idx >= n4) return;
  f32x4 v = *(const f32x4*)(in + (size_t)idx * 4);
  union { __hip_bfloat16 b[4]; unsigned long long u; } ph, pl;
#pragma unroll
  for (int j = 0; j < 4; ++j) {
    float f = v[j];
    __hip_bfloat16 hh = __float2bfloat16(f);
    ph.b[j] = hh;
    pl.b[j] = __float2bfloat16(f - __bfloat162float(hh));
  }
  *(unsigned long long*)((char*)hi + (size_t)idx * 8) = ph.u;
  if (lo) *(unsigned long long*)((char*)lo + (size_t)idx * 8) = pl.u;
}

// ---------------- split-K reduce (8 partials) -> bf16 hi (+ optional lo) ----------------
__global__ __launch_bounds__(256) void reduce8_kernel(
    const float* __restrict__ part, __hip_bfloat16* __restrict__ hi,
    __hip_bfloat16* __restrict__ lo, int n4)
{
  int idx = blockIdx.x * 256 + threadIdx.x;
  if (idx >= n4) return;
  const size_t chunk = (size_t)SEQL * DVD;   // 2048*128
  f32x4 a = *(const f32x4*)(part + (size_t)idx * 4);
#pragma unroll
  for (int z = 1; z < 8; ++z) {
    f32x4 b = *(const f32x4*)(part + z * chunk + (size_t)idx * 4);
    a.x += b.x; a.y += b.y; a.z += b.z; a.w += b.w;
  }
  union { __hip_bfloat16 b[4]; unsigned long long u; } ph, pl;
#pragma unroll
  for (int j = 0; j < 4; ++j) {
    float f = a[j];
    __hip_bfloat16 hh = __float2bfloat16(f);
    ph.b[j] = hh;
    pl.b[j] = __float2bfloat16(f - __bfloat162float(hh));
  }
  *(unsigned long long*)((char*)hi + (size_t)idx * 8) = ph.u;
  if (lo) *(unsigned long long*)((char*)lo + (size_t)idx * 8) = pl.u;
}

// ---------------- causal depthwise conv (K=4) + silu, optional ve mix ----------------
__global__ __launch_bounds__(256) void conv_silu_kernel(
    const float* __restrict__ xin, const float* __restrict__ w,
    float* __restrict__ out, const float* __restrict__ ve,
    const float* __restrict__ lambdas)
{
  int idx = blockIdx.x * 256 + threadIdx.x;          // SEQL * 512
  int s = idx >> 9, c4 = idx & 511;
  int c = c4 * 4;
  f32x4 w0 = *(const f32x4*)(w + (size_t)(c + 0) * 4);
  f32x4 w1 = *(const f32x4*)(w + (size_t)(c + 1) * 4);
  f32x4 w2 = *(const f32x4*)(w + (size_t)(c + 2) * 4);
  f32x4 w3 = *(const f32x4*)(w + (size_t)(c + 3) * 4);
  f32x4 acc = {0.f, 0.f, 0.f, 0.f};
#pragma unroll
  for (int i = 0; i < 4; ++i) {
    int sr = s - 3 + i;
    if (sr >= 0) {
      f32x4 xv = *(const f32x4*)(xin + (size_t)sr * 2048 + c);
      acc.x = fmaf(xv.x, w0[i], acc.x);
      acc.y = fmaf(xv.y, w1[i], acc.y);
      acc.z = fmaf(xv.z, w2[i], acc.z);
      acc.w = fmaf(xv.w, w3[i], acc.w);
    }
  }
  f32x4 y;
  y.x = acc.x * sigmoid_f(acc.x);
  y.y = acc.y * sigmoid_f(acc.y);
  y.z = acc.z * sigmoid_f(acc.z);
  y.w = acc.w * sigmoid_f(acc.w);
  if (ve) {
    float l0 = lambdas[0], l1 = lambdas[1];
    f32x4 vv = *(const f32x4*)(ve + (size_t)idx * 4);
    y.x = l0 * y.x + l1 * vv.x;
    y.y = l0 * y.y + l1 * vv.y;
    y.z = l0 * y.z + l1 * vv.z;
    y.w = l0 * y.w + l1 * vv.w;
  }
  *(f32x4*)(out + (size_t)idx * 4) = y;
}

// ---------------- in-place l2norm over rows of 128, one wave per row ----------------
__global__ __launch_bounds__(256) void l2norm_kernel(float* __restrict__ t, float scale)
{
  int row = blockIdx.x * 4 + (threadIdx.x >> 6);
  int lane = threadIdx.x & 63;
  float* p = t + (size_t)row * 128 + lane * 2;
  f32x2 v = *(const f32x2*)p;
  float ss = v.x * v.x + v.y * v.y;
#pragma unroll
  for (int off = 32; off > 0; off >>= 1) ss += __shfl_xor(ss, off);
  float r = rsqrtf(ss + 1e-6f) * scale;
  f32x2 o; o.x = v.x * r; o.y = v.y * r;
  *(f32x2*)p = o;
}

// ---------------- gate prep: g -> exp(-exp(A_log[h]) * softplus(g + dt_bias)) in-place ----------------
__global__ __launch_bounds__(256) void gexp_kernel(
    float* __restrict__ g, const float* __restrict__ A_log, const float* __restrict__ dt_bias)
{
  int idx = blockIdx.x * 256 + threadIdx.x;      // over S2/4
  int c4 = idx & 511;
  int cbase = c4 * 4;
  int h = cbase >> 7;
  float a = expf(A_log[h]);
  f32x4 v = *(const f32x4*)(g + (size_t)idx * 4);
  f32x4 db = *(const f32x4*)(dt_bias + cbase);
#pragma unroll
  for (int j = 0; j < 4; ++j) {
    float val = v[j] + db[j];
    float sp = (val > 20.f) ? val : log1pf(expf(fminf(val, 20.f)));
    v[j] = expf(-a * sp);
  }
  *(f32x4*)(g + (size_t)idx * 4) = v;
}

// ---------------- beta = sigmoid(x @ Wb), thread per (s,h) ----------------
__global__ __launch_bounds__(256) void beta_kernel(
    const float* __restrict__ x, const float* __restrict__ Wb, float* __restrict__ beta)
{
  int idx = blockIdx.x * 256 + threadIdx.x;      // 0..32767
  int s = idx >> 4, h = idx & 15;
  const float* xr = x + (size_t)s * DIMSZ;
  float acc = 0.f;
  for (int d = 0; d < DIMSZ; d += 4) {
    f32x4 xv = *(const f32x4*)(xr + d);
    acc = fmaf(xv.x, Wb[(size_t)(d + 0) * HN + h], acc);
    acc = fmaf(xv.y, Wb[(size_t)(d + 1) * HN + h], acc);
    acc = fmaf(xv.z, Wb[(size_t)(d + 2) * HN + h], acc);
    acc = fmaf(xv.w, Wb[(size_t)(d + 3) * HN + h], acc);
  }
  beta[idx] = 1.f / (1.f + expf(-acc));
}

// ---------------- DPP 16-lane row reduction (all lanes get the sum) ----------------
__device__ __forceinline__ float rowsum16(float x)
{
  union fi { float f; int i; };
  fi a, t; a.f = x;
  t.i = __builtin_amdgcn_update_dpp(0, a.i, 0x128, 0xf, 0xf, true); a.f += t.f; // row_ror:8
  t.i = __builtin_amdgcn_update_dpp(0, a.i, 0x124, 0xf, 0xf, true); a.f += t.f; // row_ror:4
  t.i = __builtin_amdgcn_update_dpp(0, a.i, 0x122, 0xf, 0xf, true); a.f += t.f; // row_ror:2
  t.i = __builtin_amdgcn_update_dpp(0, a.i, 0x121, 0xf, 0xf, true); a.f += t.f; // row_ror:1
  return a.f;
}

// ---------------- gated delta-rule recurrence ----------------
// 2048 independent (head, v-col) recurrences; 16 lanes/col, 8 state elems/lane.
// 8-deep register prefetch pipeline: loads for step t+8 are issued during step t,
// covering ~8 step-times (~1000cy) of L2/L3/HBM latency. All buffer indices are
// compile-time (full unroll) so the pipeline lives in VGPRs (~240 regs, fine at
// 1 block/CU -> launch_bounds(128,1)).
#define PF 8

__global__ __launch_bounds__(128, 1) void kda_rec_kernel(
    const float* __restrict__ qn, const float* __restrict__ kn,
    const float* __restrict__ vv, const float* __restrict__ ge,
    const float* __restrict__ bet, float* __restrict__ o)
{
  const int h = blockIdx.x >> 4;
  const int cg = blockIdx.x & 15;
  const int tid = threadIdx.x;
  const int col = cg * 8 + (tid >> 4);
  const int sub = tid & 15;
  const size_t base = (size_t)h * 128 + sub * 8;
  const float* pk = kn + base;
  const float* pq = qn + base;
  const float* pe = ge + base;
  const float* pv = vv + (size_t)h * 128 + col;
  const float* pb = bet + h;
  float* po = o + (size_t)h * 128 + col;

  float S0 = 0, S1 = 0, S2 = 0, S3 = 0, S4 = 0, S5 = 0, S6 = 0, S7 = 0;

  f32x4 k0b[PF], k1b[PF], e0b[PF], e1b[PF], q0b[PF], q1b[PF];
  float vb[PF], bb[PF];

#pragma unroll
  for (int i = 0; i < PF; ++i) {
    const size_t off = (size_t)i * 2048;
    k0b[i] = *(const f32x4*)(pk + off); k1b[i] = *(const f32x4*)(pk + off + 4);
    e0b[i] = *(const f32x4*)(pe + off); e1b[i] = *(const f32x4*)(pe + off + 4);
    q0b[i] = *(const f32x4*)(pq + off); q1b[i] = *(const f32x4*)(pq + off + 4);
    vb[i] = pv[off]; bb[i] = pb[(size_t)i * 16];
  }

  auto stepf = [&](int t, f32x4 k0, f32x4 k1, f32x4 e0, f32x4 e1,
                   f32x4 q0, f32x4 q1, float vt, float bt) {
    S0 *= e0.x; S1 *= e0.y; S2 *= e0.z; S3 *= e0.w;
    S4 *= e1.x; S5 *= e1.y; S6 *= e1.z; S7 *= e1.w;
    float pa = k0.x * S0; pa = fmaf(k0.y, S1, pa);
    float pb2 = k0.z * S2; pb2 = fmaf(k0.w, S3, pb2);
    float pc = k1.x * S4; pc = fmaf(k1.y, S5, pc);
    float pd = k1.z * S6; pd = fmaf(k1.w, S7, pd);
    float pred = rowsum16((pa + pb2) + (pc + pd));
    float vnew = bt * (vt - pred);
    S0 = fmaf(k0.x, vnew, S0); S1 = fmaf(k0.y, vnew, S1);
    S2 = fmaf(k0.z, vnew, S2); S3 = fmaf(k0.w, vnew, S3);
    S4 = fmaf(k1.x, vnew, S4); S5 = fmaf(k1.y, vnew, S5);
    S6 = fmaf(k1.z, vnew, S6); S7 = fmaf(k1.w, vnew, S7);
    float oa = q0.x * S0; oa = fmaf(q0.y, S1, oa);
    float ob = q0.z * S2; ob = fmaf(q0.w, S3, ob);
    float oc = q1.x * S4; oc = fmaf(q1.y, S5, oc);
    float od = q1.z * S6; od = fmaf(q1.w, S7, od);
    float out = rowsum16((oa + ob) + (oc + od));
    if (sub == 0) po[(size_t)t * 2048] = out;
  };

  // steady state: unconditional prefetch of t+PF
  for (int t0 = 0; t0 < SEQL - PF; t0 += PF) {
#pragma unroll
    for (int i = 0; i < PF; ++i) {
      const int t = t0 + i;
      const f32x4 k0 = k0b[i], k1 = k1b[i], e0 = e0b[i], e1 = e1b[i];
      const f32x4 q0 = q0b[i], q1 = q1b[i];
      const float vt = vb[i], bt = bb[i];
      const size_t off = (size_t)(t + PF) * 2048;
      k0b[i] = *(const f32x4*)(pk + off); k1b[i] = *(const f32x4*)(pk + off + 4);
      e0b[i] = *(const f32x4*)(pe + off); e1b[i] = *(const f32x4*)(pe + off + 4);
      q0b[i] = *(const f32x4*)(pq + off); q1b[i] = *(const f32x4*)(pq + off + 4);
      vb[i] = pv[off]; bb[i] = pb[(size_t)(t + PF) * 16];
      stepf(t, k0, k1, e0, e1, q0, q1, vt, bt);
    }
  }
  // epilogue: last PF steps, no prefetch
#pragma unroll
  for (int i = 0; i < PF; ++i) {
    const int t = SEQL - PF + i;
    stepf(t, k0b[i], k1b[i], e0b[i], e1b[i], q0b[i], q1b[i], vb[i], bb[i]);
  }
}

// ---------------- sigmoid-gated RMSNorm -> bf16 ----------------
__global__ __launch_bounds__(256) void rmsgate_kernel(
    const float* __restrict__ o, const float* __restrict__ gate,
    const float* __restrict__ bg2, const float* __restrict__ norm_w,
    __hip_bfloat16* __restrict__ og)
{
  int row = blockIdx.x * 4 + (threadIdx.x >> 6);   // s*16 + h
  int lane = threadIdx.x & 63;
  int s = row >> 4, h = row & 15;
  int j = lane * 2;
  const float* p = o + (size_t)row * 128 + j;
  f32x2 v = *(const f32x2*)p;
  float ss = v.x * v.x + v.y * v.y;
#pragma unroll
  for (int off = 32; off > 0; off >>= 1) ss += __shfl_xor(ss, off);
  float rs = rsqrtf(ss * (1.f / 128.f) + 1e-6f);
  int c = h * 128 + j;
  float g0 = gate[(size_t)s * 2048 + c] + bg2[c];
  float g1 = gate[(size_t)s * 2048 + c + 1] + bg2[c + 1];
  float o0 = v.x * rs * norm_w[j] * (1.f / (1.f + expf(-g0)));
  float o1 = v.y * rs * norm_w[j + 1] * (1.f / (1.f + expf(-g1)));
  union { __hip_bfloat16 b[2]; unsigned int u; } pk2;
  pk2.b[0] = __float2bfloat16(o0);
  pk2.b[1] = __float2bfloat16(o1);
  *(unsigned int*)((char*)og + ((size_t)s * 2048 + c) * 2) = pk2.u;
}

// =====================================================================
extern "C" void kernel_launch(void* const* d_in, const int* in_sizes, int n_in,
                              void* d_out, int out_size, void* d_ws, size_t ws_size,
                              hipStream_t stream)
{
  const float* x      = (const float*)d_in[0];
  const float* ve     = (const float*)d_in[1];
  const float* lam    = (const float*)d_in[2];
  const float* Wq     = (const float*)d_in[3];
  const float* Wk     = (const float*)d_in[4];
  const float* Wv     = (const float*)d_in[5];
  const float* cwq    = (const float*)d_in[6];
  const float* cwk    = (const float*)d_in[7];
  const float* cwv    = (const float*)d_in[8];
  const float* Wf1    = (const float*)d_in[9];
  const float* Wf2    = (const float*)d_in[10];
  const float* Wb     = (const float*)d_in[11];
  const float* A_log  = (const float*)d_in[12];
  const float* dtb    = (const float*)d_in[13];
  const float* Wg1    = (const float*)d_in[14];
  const float* Wg2    = (const float*)d_in[15];
  const float* bg2    = (const float*)d_in[16];
  const float* norm_w = (const float*)d_in[17];
  const float* Wo     = (const float*)d_in[18];
  float* out = (float*)d_out;

  const size_t S2 = (size_t)2048 * 2048;

  char* p = (char*)d_ws;
  auto alloc = [&](size_t bytes) { char* r = p; p += (bytes + 255) & ~(size_t)255; return r; };

  __hip_bfloat16* xb    = (__hip_bfloat16*)alloc(S2 * 2);
  __hip_bfloat16* xlo   = (__hip_bfloat16*)alloc(S2 * 2);
  __hip_bfloat16* WqT   = (__hip_bfloat16*)alloc(S2 * 2);
  __hip_bfloat16* WkT   = (__hip_bfloat16*)alloc(S2 * 2);
  __hip_bfloat16* WvT   = (__hip_bfloat16*)alloc(S2 * 2);
  __hip_bfloat16* WoT   = (__hip_bfloat16*)alloc(S2 * 2);
  __hip_bfloat16* Wf1hT = (__hip_bfloat16*)alloc(2048 * 128 * 2);
  __hip_bfloat16* Wf1lT = (__hip_bfloat16*)alloc(2048 * 128 * 2);
  __hip_bfloat16* Wf2hT = (__hip_bfloat16*)alloc(2048 * 128 * 2);
  __hip_bfloat16* Wf2lT = (__hip_bfloat16*)alloc(2048 * 128 * 2);
  __hip_bfloat16* Wg1T  = (__hip_bfloat16*)alloc(2048 * 128 * 2);
  __hip_bfloat16* Wg2T  = (__hip_bfloat16*)alloc(2048 * 128 * 2);
  float* xq   = (float*)alloc(S2 * 4);   // later aliased: g / gexp
  float* xk   = (float*)alloc(S2 * 4);   // later aliased: gate
  float* xv   = (float*)alloc(S2 * 4);   // later aliased: o
  float* cq   = (float*)alloc(S2 * 4);
  float* ck   = (float*)alloc(S2 * 4);
  float* cv   = (float*)alloc(S2 * 4);
  __hip_bfloat16* f1h = (__hip_bfloat16*)alloc(2048 * 128 * 2);
  __hip_bfloat16* f1l = (__hip_bfloat16*)alloc(2048 * 128 * 2);
  __hip_bfloat16* g1b = (__hip_bfloat16*)alloc(2048 * 128 * 2);
  float* fpart = (float*)alloc((size_t)8 * 2048 * 128 * 4);
  float* betab = (float*)alloc((size_t)2048 * 16 * 4);
  __hip_bfloat16* og = (__hip_bfloat16*)alloc(S2 * 2);

  float* gbuf    = xq;   // aliases (dead after convs)
  float* gatebuf = xk;
  float* obuf    = xv;

  // 1. split-cast x
  cast_split_kernel<<<4096, 256, 0, stream>>>(x, xb, xlo, (int)(S2 / 4));

  // 2. weight transposes (+ hi/lo for the decay path)
  transpose_cast_kernel<<<dim3(64, 64), 256, 0, stream>>>(Wq, WqT, nullptr, 2048, 2048);
  transpose_cast_kernel<<<dim3(64, 64), 256, 0, stream>>>(Wk, WkT, nullptr, 2048, 2048);
  transpose_cast_kernel<<<dim3(64, 64), 256, 0, stream>>>(Wv, WvT, nullptr, 2048, 2048);
  transpose_cast_kernel<<<dim3(64, 64), 256, 0, stream>>>(Wo, WoT, nullptr, 2048, 2048);
  transpose_cast_kernel<<<dim3(4, 64), 256, 0, stream>>>(Wf1, Wf1hT, Wf1lT, 2048, 128);
  transpose_cast_kernel<<<dim3(64, 4), 256, 0, stream>>>(Wf2, Wf2hT, Wf2lT, 128, 2048);
  transpose_cast_kernel<<<dim3(4, 64), 256, 0, stream>>>(Wg1, Wg1T, nullptr, 2048, 128);
  transpose_cast_kernel<<<dim3(64, 4), 256, 0, stream>>>(Wg2, Wg2T, nullptr, 128, 2048);

  // 3. projection GEMMs
  gemm_bt<<<dim3(16, 16), 256, 0, stream>>>(xb, WqT, xq, 2048, 2048, 2048, 2048, 0);
  gemm_bt<<<dim3(16, 16), 256, 0, stream>>>(xb, WkT, xk, 2048, 2048, 2048, 2048, 0);
  gemm_bt<<<dim3(16, 16), 256, 0, stream>>>(xb, WvT, xv, 2048, 2048, 2048, 2048, 0);

  // 4. conv + silu (+ ve mix for v)
  conv_silu_kernel<<<4096, 256, 0, stream>>>(xq, cwq, cq, nullptr, nullptr);
  conv_silu_kernel<<<4096, 256, 0, stream>>>(xk, cwk, ck, nullptr, nullptr);
  conv_silu_kernel<<<4096, 256, 0, stream>>>(xv, cwv, cv, ve, lam);

  // 5. l2 norms
  l2norm_kernel<<<8192, 256, 0, stream>>>(cq, QSCALE);
  l2norm_kernel<<<8192, 256, 0, stream>>>(ck, 1.0f);

  // 6. f1 = x @ Wf1 (split precision, split-K z=8)
  gemm_bt<<<dim3(1, 16, 8), 256, 0, stream>>>(xb,  Wf1hT, fpart, 2048, 128, 2048, 256, 0);
  gemm_bt<<<dim3(1, 16, 8), 256, 0, stream>>>(xlo, Wf1hT, fpart, 2048, 128, 2048, 256, 1);
  gemm_bt<<<dim3(1, 16, 8), 256, 0, stream>>>(xb,  Wf1lT, fpart, 2048, 128, 2048, 256, 1);
  reduce8_kernel<<<256, 256, 0, stream>>>(fpart, f1h, f1l, 65536);

  // 7. g = f1 @ Wf2 (split precision) -> gbuf, then gate-exp in place
  gemm_bt<<<dim3(16, 16), 256, 0, stream>>>(f1h, Wf2hT, gbuf, 2048, 2048, 128, 128, 0);
  gemm_bt<<<dim3(16, 16), 256, 0, stream>>>(f1l, Wf2hT, gbuf, 2048, 2048, 128, 128, 1);
  gemm_bt<<<dim3(16, 16), 256, 0, stream>>>(f1h, Wf2lT, gbuf, 2048, 2048, 128, 128, 1);
  gexp_kernel<<<4096, 256, 0, stream>>>(gbuf, A_log, dtb);

  // 8. gate path (plain bf16 is fine through a sigmoid)
  gemm_bt<<<dim3(1, 16, 8), 256, 0, stream>>>(xb, Wg1T, fpart, 2048, 128, 2048, 256, 0);
  reduce8_kernel<<<256, 256, 0, stream>>>(fpart, g1b, nullptr, 65536);
  gemm_bt<<<dim3(16, 16), 256, 0, stream>>>(g1b, Wg2T, gatebuf, 2048, 2048, 128, 128, 0);

  // 9. beta
  beta_kernel<<<128, 256, 0, stream>>>(x, Wb, betab);

  // 10. recurrence
  kda_rec_kernel<<<256, 128, 0, stream>>>(cq, ck, cv, gbuf, betab, obuf);

  // 11. gated rmsnorm -> bf16
  rmsgate_kernel<<<8192, 256, 0, stream>>>(obuf, gatebuf, bg2, norm_w, og);

  // 12. output projection
  gemm_bt<<<dim3(16, 16), 256, 0, stream>>>(og, WoT, out, 2048, 2048, 2048, 2048, 0);
}